// Round 6
// baseline (228.878 us; speedup 1.0000x reference)
//
#include <hip/hip_runtime.h>
#include <math.h>

// Problem constants (B=8,S=4096,D=1024,E=64,G=4,K=2, temperature=1)
#define TOKENS   32768
#define DDIM     1024
#define TPB      64                   // tokens per block
#define NBLOCKS  (TOKENS / TPB)       // 512 blocks x 256 threads (4 waves: khalf x mhalf)

// Output layout (flat float32, tuple concat: idx, scores, probs, importance, load)
#define OFF_SCORES 65536
#define OFF_PROBS  131072
#define OFF_IMP    2228224
#define OFF_LOAD   2228288

#define NSLOT 16              // atomic spreading for importance/load partials

typedef __attribute__((ext_vector_type(8))) short  short8;  // 8 bf16 = 4 VGPR (MFMA A/B frag)
typedef __attribute__((ext_vector_type(4))) float  f32x4;   // MFMA C/D frag
typedef __attribute__((ext_vector_type(4))) int    intx4;

// Pre-split W fragments: [gstep(32)][frag(16)][lane(64)] x 16B = 512 KB, L2-resident.
// frag = nt*3+lvl (0..14); frag 15 = zero pad (so each wave stages a uniform
// 8 chunks via global_load_lds). Rows 0..63 = experts, 64..67 = groups.
__device__ __attribute__((aligned(16))) short wfrag[32 * 16 * 64 * 8];

// Direct global->LDS DMA, 16B/lane. LDS dest is wave-uniform base + lane*16
// (m104); our chunk layout [c*64+lane] is exactly that. Compiler never
// auto-emits this (Common-mistake #1).
__device__ inline void stage16(const void* g, void* l) {
  __builtin_amdgcn_global_load_lds(
      (const __attribute__((address_space(1))) void*)g,
      (__attribute__((address_space(3))) void*)l, 16, 0, 0);
}

// bf16 round-to-nearest-even of x, returned as the fp32 bit pattern.
__device__ inline unsigned rne_hi(float x) {
  unsigned u = __float_as_uint(x);
  unsigned r = u + 0x7fffu + ((u >> 16) & 1u);
  return r & 0xffff0000u;
}

// Split x (fp32) into 3 RNE-bf16 terms: x = a1 + a2 + a3 + O(2^-27 |x|).
__device__ inline void split3(const float* xv, short8& f1, short8& f2, short8& f3) {
  int o1[4], o2[4], o3[4];
  #pragma unroll
  for (int p = 0; p < 4; ++p) {
    float x0 = xv[2*p], x1 = xv[2*p+1];
    unsigned h0 = rne_hi(x0), h1 = rne_hi(x1);
    o1[p] = (int)((h0 >> 16) | (h1 & 0xffff0000u));
    float r0 = x0 - __uint_as_float(h0);
    float r1 = x1 - __uint_as_float(h1);
    unsigned g0 = rne_hi(r0), g1 = rne_hi(r1);
    o2[p] = (int)((g0 >> 16) | (g1 & 0xffff0000u));
    float s0 = r0 - __uint_as_float(g0);
    float s1 = r1 - __uint_as_float(g1);
    unsigned w0 = rne_hi(s0), w1 = rne_hi(s1);
    o3[p] = (int)((w0 >> 16) | (w1 & 0xffff0000u));
  }
  intx4 t1 = {o1[0], o1[1], o1[2], o1[3]};
  intx4 t2 = {o2[0], o2[1], o2[2], o2[3]};
  intx4 t3 = {o3[0], o3[1], o3[2], o3[3]};
  f1 = __builtin_bit_cast(short8, t1);
  f2 = __builtin_bit_cast(short8, t2);
  f3 = __builtin_bit_cast(short8, t3);
}

// Build W fragment splits. 160 blocks (nt*32+ks) x 64 threads.
// Blocks 0..31 also zero the ws accumulators; block 0 zeroes the ticket.
__global__ void prep_kernel(const float* __restrict__ Wg, const float* __restrict__ We,
                            float* __restrict__ ws) {
  const int nt   = blockIdx.x >> 5;   // 0..4
  const int ks   = blockIdx.x & 31;   // 0..31 (global k-step)
  const int lane = threadIdx.x & 63;
  if (blockIdx.x < 32) ws[blockIdx.x * 64 + lane] = 0.f;   // NSLOT*128 = 2048 floats
  if (blockIdx.x == 0 && threadIdx.x == 0) ((unsigned*)ws)[2048] = 0u;  // ticket
  const int row  = nt * 16 + (lane & 15);
  const int k0   = ks * 32 + (lane >> 4) * 8;
  float xv[8];
  #pragma unroll
  for (int j = 0; j < 8; ++j) {
    float v = 0.f;
    if (row < 64)      v = We[(size_t)row * DDIM + k0 + j];
    else if (row < 68) v = Wg[(size_t)(row - 64) * DDIM + k0 + j];
    xv[j] = v;
  }
  short8 f1, f2, f3;
  split3(xv, f1, f2, f3);
  short8* dst = (short8*)wfrag + ((size_t)ks * 16 + nt * 3) * 64 + lane;
  dst[0]   = f1;
  dst[64]  = f2;
  dst[128] = f3;
  if (nt == 4) {  // zero pad frag 15 of this k-step
    short8 z = {};
    ((short8*)wfrag)[((size_t)ks * 16 + 15) * 64 + lane] = z;
  }
}

// Bit-exact per-token arithmetic vs the verified kernel (identical per-
// accumulator MFMA chain order, sequential ks per khalf, el=S1; el+=S0
// combine, identical epilogue). Round-6 structural changes:
//  - B staging via global_load_lds (16B/lane DMA): deletes breg (-32 VGPR
//    peak pressure -> under the 256 cap at waves_per_eu(2), no spill) and
//    all ds_writes (-64 KB/CU/step DS-instruction traffic). Plain
//    __syncthreads kept (R5 showed the vmcnt drain is ~free; avoids the
//    hand-counted-vmcnt race surface).
//  - finalize fused via device-scope ticket: last of the 512 blocks reduces
//    the ws slots in the identical s=0..15 order (bit-identical), saving a
//    full dispatch (~8-10 us of launch gap at this harness).
__global__ __launch_bounds__(256)
__attribute__((amdgpu_waves_per_eu(2)))
void router_kernel(const float* __restrict__ x,
                   float* __restrict__ out,
                   float* __restrict__ ws) {
  // [0,65536) = bstage dbuf (2 bufs x 32 chunks x 64 lanes x 16B);
  // el (64*88*4 = 22528 B) overlays buf0, used only after the loop.
  __shared__ __attribute__((aligned(16))) char smem[65536 + 384];
  float*  el     = (float*)smem;
  short8* bstage = (short8*)smem;           // chunk c of buf b at [b*2048 + c*64 + lane]
  int*    cnt    = (int*)(smem + 65536);    // 64 counts + [64] = last-block flag
  const int tid    = threadIdx.x;
  const int lane   = tid & 63;
  const int wv     = tid >> 6;      // 0..3
  const int khalf  = wv >> 1;       // K-half (512-wide, sequential 16 k-steps)
  const int mhalf  = wv & 1;        // which pair of 16-token m-tiles
  const int quad   = lane >> 4;
  const int m      = lane & 15;
  const int tokblk = blockIdx.x * TPB;

  if (tid < 64) cnt[tid] = 0;

  // MFMA A-operand gather: lane holds A[row=m][k=quad*8+j]; two 16-token m-tiles.
  const float* apb = x + (size_t)(tokblk + mhalf * 32 + m) * DDIM + khalf * 512 + quad * 8;
  const short* wsrc = wfrag;

  // a1b1 chain isolated in ahi; all cross terms in alo (verified numerics).
  f32x4 ahi[2][5], alo[2][5];
  #pragma unroll
  for (int mt = 0; mt < 2; ++mt)
    #pragma unroll
    for (int nt = 0; nt < 5; ++nt) { ahi[mt][nt] = 0.f; alo[mt][nt] = 0.f; }

  // A for ks=0
  float4 cur[4], nxt[4];
  #pragma unroll
  for (int mt = 0; mt < 2; ++mt) {
    const float* p = apb + (size_t)(mt * 16) * DDIM;
    cur[mt * 2]     = *(const float4*)(p);
    cur[mt * 2 + 1] = *(const float4*)(p + 4);
  }

  // Prologue: DMA-stage ks=0 B into buf0. chunk c = wv + 4*j (uniform 8 per
  // wave); c<16 -> khalf0 frag c of gstep ks, c>=16 -> khalf1 frag c-16 of
  // gstep 16+ks. LDS dest base is wave-uniform; lane*16 appended by HW.
  #pragma unroll
  for (int j = 0; j < 8; ++j) {
    const int c = wv + 4 * j;
    const int G = ((c < 16) ? 0 : 16) * 16 + (c & 15) * 1 + ((c < 16) ? 0 : 0) * 0;  // gstep*16+frag
    const int gstep = (c < 16) ? 0 : 16;
    const short* gs = wsrc + ((size_t)(gstep * 16 + (c & 15)) * 64 + lane) * 8;
    stage16(gs, smem + c * 1024);
    (void)G;
  }
  __syncthreads();

  for (int ks = 0; ks < 16; ++ks) {
    const int pb = ks & 1;
    // ---- issue next-step DMA staging + A prefetch (top of step) ----
    if (ks < 15) {
      #pragma unroll
      for (int j = 0; j < 8; ++j) {
        const int c = wv + 4 * j;
        const int gstep = ((c < 16) ? 0 : 16) + ks + 1;
        const short* gs = wsrc + ((size_t)(gstep * 16 + (c & 15)) * 64 + lane) * 8;
        stage16(gs, smem + (pb ^ 1) * 32768 + c * 1024);
      }
      #pragma unroll
      for (int mt = 0; mt < 2; ++mt) {
        const float* p = apb + (size_t)(mt * 16) * DDIM + (ks + 1) * 32;
        nxt[mt * 2]     = *(const float4*)(p);
        nxt[mt * 2 + 1] = *(const float4*)(p + 4);
      }
    }
    // ---- split3 for both m-tiles ----
    short8 fa[2][3];
    #pragma unroll
    for (int mt = 0; mt < 2; ++mt) {
      float av[8] = {cur[mt*2].x, cur[mt*2].y, cur[mt*2].z, cur[mt*2].w,
                     cur[mt*2+1].x, cur[mt*2+1].y, cur[mt*2+1].z, cur[mt*2+1].w};
      split3(av, fa[mt][0], fa[mt][1], fa[mt][2]);
    }
    // ---- nt loop, per-nt fb streaming from buf[pb] ----
    const short8* bbase = &bstage[(size_t)pb * 2048 + (size_t)khalf * 16 * 64 + lane];
    short8 fb0 = bbase[0], fb1 = bbase[64], fb2 = bbase[128];
    #pragma unroll
    for (int nt = 0; nt < 5; ++nt) {
      short8 n0, n1, n2;
      if (nt < 4) {
        n0 = bbase[(nt + 1) * 192];
        n1 = bbase[(nt + 1) * 192 + 64];
        n2 = bbase[(nt + 1) * 192 + 128];
      }
      // 8-pass split MFMA: a1b1 -> hi; cross terms -> lo (a3b3 dropped).
      // Per-accumulator chain order preserved exactly (bit-exact).
      #pragma unroll
      for (int mt = 0; mt < 2; ++mt) {
        ahi[mt][nt] = __builtin_amdgcn_mfma_f32_16x16x32_bf16(fa[mt][0], fb0, ahi[mt][nt], 0, 0, 0);
        f32x4 c = alo[mt][nt];
        c = __builtin_amdgcn_mfma_f32_16x16x32_bf16(fa[mt][0], fb1, c, 0, 0, 0);
        c = __builtin_amdgcn_mfma_f32_16x16x32_bf16(fa[mt][1], fb0, c, 0, 0, 0);
        c = __builtin_amdgcn_mfma_f32_16x16x32_bf16(fa[mt][1], fb1, c, 0, 0, 0);
        c = __builtin_amdgcn_mfma_f32_16x16x32_bf16(fa[mt][0], fb2, c, 0, 0, 0);
        c = __builtin_amdgcn_mfma_f32_16x16x32_bf16(fa[mt][2], fb0, c, 0, 0, 0);
        c = __builtin_amdgcn_mfma_f32_16x16x32_bf16(fa[mt][1], fb2, c, 0, 0, 0);
        c = __builtin_amdgcn_mfma_f32_16x16x32_bf16(fa[mt][2], fb1, c, 0, 0, 0);
        alo[mt][nt] = c;
      }
      if (nt < 4) { fb0 = n0; fb1 = n1; fb2 = n2; }
    }
    // ---- single barrier per step: drains this step's DMA into buf[pb^1] ----
    if (ks < 15) {
      __syncthreads();
      #pragma unroll
      for (int i = 0; i < 4; ++i) cur[i] = nxt[i];
    }
  }

  // ---- K-half combine, verified order: el = S1; el += S0 ----
  // Union-safe: step 15 read only buf1 (bytes 32768+); el (22528 B) sits in
  // buf0, whose last readers retired at the end-of-ks=14 barrier and whose
  // last DMA writes (ks=13 staging) drained at the ks=13 barrier.
  // C/D layout: col(n)=lane&15, row(m)=quad*4+reg
  if (khalf == 1) {
    #pragma unroll
    for (int mt = 0; mt < 2; ++mt)
      #pragma unroll
      for (int nt = 0; nt < 5; ++nt)
        #pragma unroll
        for (int r = 0; r < 4; ++r)
          el[(mhalf * 32 + mt * 16 + quad * 4 + r) * 88 + nt * 16 + m] = ahi[mt][nt][r] + alo[mt][nt][r];
  }
  __syncthreads();
  if (khalf == 0) {
    #pragma unroll
    for (int mt = 0; mt < 2; ++mt)
      #pragma unroll
      for (int nt = 0; nt < 5; ++nt)
        #pragma unroll
        for (int r = 0; r < 4; ++r) {
          const int idx = (mhalf * 32 + mt * 16 + quad * 4 + r) * 88 + nt * 16 + m;
          el[idx] += ahi[mt][nt][r] + alo[mt][nt][r];
        }
  }
  __syncthreads();

  // ---- epilogue: one token per thread (tid<64) ----
  if (tid < TPB) {
    const int t = tid;
    float* row = el + t * 88;
    const float g0 = row[64], g1 = row[65], g2 = row[66], g3 = row[67];
    int g = 0; float gb = g0;
    if (g1 > gb) { g = 1; gb = g1; }
    if (g2 > gb) { g = 2; gb = g2; }
    if (g3 > gb) { g = 3; gb = g3; }
    const int base = g << 4;
    float l[16];
    #pragma unroll
    for (int e = 0; e < 16; ++e) l[e] = row[base + e];
    int i1 = 0; float v1 = l[0];
    #pragma unroll
    for (int e = 1; e < 16; ++e) if (l[e] > v1) { i1 = e; v1 = l[e]; }
    int i2 = -1; float v2 = 0.f;
    #pragma unroll
    for (int e = 0; e < 16; ++e) {
      if (e == i1) continue;
      if (i2 < 0 || l[e] > v2) { i2 = e; v2 = l[e]; }
    }
    float pr[16]; float s = 0.f;
    #pragma unroll
    for (int e = 0; e < 16; ++e) { pr[e] = expf(l[e] - v1); s += pr[e]; }
    const float inv = 1.f / s;
    #pragma unroll
    for (int c = 0; c < 64; ++c) row[c] = 0.f;
    #pragma unroll
    for (int e = 0; e < 16; ++e) row[base + e] = pr[e] * inv;
    const size_t T = (size_t)tokblk + t;
    out[2*T]     = (float)(base + i1);
    out[2*T + 1] = (float)(base + i2);
    const float e2 = expf(v2 - v1);
    const float si = 1.f / (1.f + e2);
    out[OFF_SCORES + 2*T]     = si;
    out[OFF_SCORES + 2*T + 1] = e2 * si;
    atomicAdd(&cnt[base + i1], 1);
    atomicAdd(&cnt[base + i2], 1);
  }
  __syncthreads();

  // coalesced probs_full write (256 threads, 16 iters)
  for (int i = tid; i < TPB * 64; i += 256) {
    const int t = i >> 6, c = i & 63;
    out[OFF_PROBS + (((size_t)(tokblk + t)) << 6) + c] = el[t * 88 + c];
  }
  // block-partial importance & counts -> slot-spread global atomics
  // (512 blocks / 16 slots = 32-way contention, verified scheme)
  if (tid < 64) {
    const int e = tid;
    float s = 0.f;
    #pragma unroll 4
    for (int t = 0; t < TPB; ++t) s += el[t * 88 + e];
    const int slot = (blockIdx.x & (NSLOT - 1)) * 128;
    atomicAdd(&ws[slot + e], s);
    atomicAdd(&ws[slot + 64 + e], (float)cnt[e]);
  }

  // ---- fused finalize: last block reduces the slots (saves a dispatch) ----
  __syncthreads();   // drain this block's ws atomics (vmcnt(0) at barrier)
  if (tid == 0) {
    __threadfence();
    unsigned prev = __hip_atomic_fetch_add((unsigned*)(ws + 2048), 1u,
                                           __ATOMIC_ACQ_REL, __HIP_MEMORY_SCOPE_AGENT);
    cnt[64] = (prev == (unsigned)(NBLOCKS - 1)) ? 1 : 0;
  }
  __syncthreads();
  if (cnt[64] && tid < 64) {
    const int e = tid;
    float imp = 0.f, cf = 0.f;
    #pragma unroll
    for (int s = 0; s < NSLOT; ++s) {   // identical order to the old finalize
      imp += __hip_atomic_load(&ws[s * 128 + e],      __ATOMIC_RELAXED, __HIP_MEMORY_SCOPE_AGENT);
      cf  += __hip_atomic_load(&ws[s * 128 + 64 + e], __ATOMIC_RELAXED, __HIP_MEMORY_SCOPE_AGENT);
    }
    out[OFF_IMP  + e] = imp * (1.0f / 32768.0f);
    out[OFF_LOAD + e] = cf  * (1.0f / 65536.0f);   // counts sum == B*S*K
  }
}

extern "C" void kernel_launch(void* const* d_in, const int* in_sizes, int n_in,
                              void* d_out, int out_size, void* d_ws, size_t ws_size,
                              hipStream_t stream) {
  (void)in_sizes; (void)n_in; (void)out_size; (void)ws_size;
  const float* x  = (const float*)d_in[0];   // [8,4096,1024]
  const float* Wg = (const float*)d_in[1];   // [4,1024]
  const float* We = (const float*)d_in[2];   // [64,1024]
  float* out = (float*)d_out;
  float* ws  = (float*)d_ws;                 // NSLOT x 128 floats + ticket at [2048]
  hipLaunchKernelGGL(prep_kernel, dim3(160), dim3(64), 0, stream, Wg, We, ws);
  hipLaunchKernelGGL(router_kernel, dim3(NBLOCKS), dim3(256), 0, stream, x, out, ws);
}

// Round 8
// 227.667 us; speedup vs baseline: 1.0053x; 1.0053x over previous
//
#include <hip/hip_runtime.h>
#include <math.h>

// Problem constants (B=8,S=4096,D=1024,E=64,G=4,K=2, temperature=1)
#define TOKENS   32768
#define DDIM     1024
#define TPB      64                   // tokens per block
#define NBLOCKS  (TOKENS / TPB)       // 512 blocks x 256 threads (4 waves: khalf x mhalf)

// Output layout (flat float32, tuple concat: idx, scores, probs, importance, load)
#define OFF_SCORES 65536
#define OFF_PROBS  131072
#define OFF_IMP    2228224
#define OFF_LOAD   2228288

#define NSLOT 16              // atomic spreading for importance/load partials

typedef __attribute__((ext_vector_type(8))) short  short8;  // 8 bf16 = 4 VGPR (MFMA A/B frag)
typedef __attribute__((ext_vector_type(4))) float  f32x4;   // MFMA C/D frag
typedef __attribute__((ext_vector_type(4))) int    intx4;

// Pre-split W fragments: [ks(32)][nt(5)][lvl(3)][lane(64)] x 16B. 480 KB, L2-resident.
// Rows 0..63 = experts, 64..67 = groups, 68..79 = zero pad.
__device__ __attribute__((aligned(16))) short wfrag[32 * 5 * 3 * 64 * 8];

// Raw workgroup barrier WITHOUT the vmcnt(0) drain __syncthreads emits.
// LDS producer->consumer ordering needs only lgkmcnt(0); global loads (depth-2
// A ring, breg) stay in flight ACROSS barriers. R5-verified race-safe; it only
// pays combined with depth-2 prefetch (R5 alone was null: depth-1 A is
// consumed right after the barrier, so nothing usefully stayed in flight).
__device__ inline void barrier_nodrain() {
  asm volatile("s_waitcnt lgkmcnt(0)" ::: "memory");
  __builtin_amdgcn_sched_barrier(0);
  __builtin_amdgcn_s_barrier();
  __builtin_amdgcn_sched_barrier(0);
}

// bf16 round-to-nearest-even of x, returned as the fp32 bit pattern.
__device__ inline unsigned rne_hi(float x) {
  unsigned u = __float_as_uint(x);
  unsigned r = u + 0x7fffu + ((u >> 16) & 1u);
  return r & 0xffff0000u;
}

// Split x (fp32) into 3 RNE-bf16 terms: x = a1 + a2 + a3 + O(2^-27 |x|).
__device__ inline void split3(const float* xv, short8& f1, short8& f2, short8& f3) {
  int o1[4], o2[4], o3[4];
  #pragma unroll
  for (int p = 0; p < 4; ++p) {
    float x0 = xv[2*p], x1 = xv[2*p+1];
    unsigned h0 = rne_hi(x0), h1 = rne_hi(x1);
    o1[p] = (int)((h0 >> 16) | (h1 & 0xffff0000u));
    float r0 = x0 - __uint_as_float(h0);
    float r1 = x1 - __uint_as_float(h1);
    unsigned g0 = rne_hi(r0), g1 = rne_hi(r1);
    o2[p] = (int)((g0 >> 16) | (g1 & 0xffff0000u));
    float s0 = r0 - __uint_as_float(g0);
    float s1 = r1 - __uint_as_float(g1);
    unsigned w0 = rne_hi(s0), w1 = rne_hi(s1);
    o3[p] = (int)((w0 >> 16) | (w1 & 0xffff0000u));
  }
  intx4 t1 = {o1[0], o1[1], o1[2], o1[3]};
  intx4 t2 = {o2[0], o2[1], o2[2], o2[3]};
  intx4 t3 = {o3[0], o3[1], o3[2], o3[3]};
  f1 = __builtin_bit_cast(short8, t1);
  f2 = __builtin_bit_cast(short8, t2);
  f3 = __builtin_bit_cast(short8, t3);
}

// Build W fragment splits. 160 blocks (nt*32+ks) x 64 threads.
// Blocks 0..31 also zero the ws accumulators; block 0 zeroes the ticket.
__global__ void prep_kernel(const float* __restrict__ Wg, const float* __restrict__ We,
                            float* __restrict__ ws) {
  const int nt   = blockIdx.x >> 5;   // 0..4
  const int ks   = blockIdx.x & 31;   // 0..31
  const int lane = threadIdx.x & 63;
  if (blockIdx.x < 32) ws[blockIdx.x * 64 + lane] = 0.f;   // NSLOT*128 = 2048 floats
  if (blockIdx.x == 0 && threadIdx.x == 0) ((unsigned*)ws)[2048] = 0u;  // ticket
  const int row  = nt * 16 + (lane & 15);
  const int k0   = ks * 32 + (lane >> 4) * 8;
  float xv[8];
  #pragma unroll
  for (int j = 0; j < 8; ++j) {
    float v = 0.f;
    if (row < 64)      v = We[(size_t)row * DDIM + k0 + j];
    else if (row < 68) v = Wg[(size_t)(row - 64) * DDIM + k0 + j];
    xv[j] = v;
  }
  short8 f1, f2, f3;
  split3(xv, f1, f2, f3);
  short8* dst = (short8*)wfrag + (((size_t)ks * 5 + nt) * 3) * 64 + lane;
  dst[0]   = f1;
  dst[64]  = f2;
  dst[128] = f3;
}

// Bit-exact per-token arithmetic vs the verified R4 kernel (identical per-
// accumulator MFMA chain order, sequential ks per khalf, el=S1; el+=S0
// combine, identical epilogue). R7's lesson: the summation association is
// UNTOUCHABLE (a ~1e-6 reassociation flipped a top-k tie -> idx fail).
// Round-8 = R4 + three individually-verified structural changes:
//  - barrier_nodrain in the K-loop (R5): keeps global loads in flight across
//    the per-step barrier,
//  - depth-2 A-prefetch ring (cur/nx1/nx2): the load issued at step ks is
//    consumed at ks+2, giving a full extra step (~5-7Kcy) of flight to cover
//    the ~900cy HBM miss latency (L3 is thrashed each iteration by the
//    harness's 512MiB poison fill -> FETCH 67MB, half of x from HBM),
//  - R6's ticket-fused finalize: last block reduces ws slots in the identical
//    s=0..15 order (bit-identical), saving one dispatch of fixed overhead.
__global__ __launch_bounds__(256)
__attribute__((amdgpu_waves_per_eu(2)))
void router_kernel(const float* __restrict__ x,
                   float* __restrict__ out,
                   float* __restrict__ ws) {
  // union: [0,61440) = bstage dbuf (2 x 30 chunks x 64 lanes x 16B);
  //        el (64*88*4 = 22528 B) overlays buf0, used only after the loop.
  __shared__ __attribute__((aligned(16))) char smem[61440 + 384];
  float*  el     = (float*)smem;
  short8* bstage = (short8*)smem;
  int*    cnt    = (int*)(smem + 61440);   // 64 counts + [64] last-block flag
  const int tid    = threadIdx.x;
  const int lane   = tid & 63;
  const int wv     = tid >> 6;      // 0..3
  const int khalf  = wv >> 1;       // K-half (512-wide, sequential 16 k-steps)
  const int mhalf  = wv & 1;        // which pair of 16-token m-tiles
  const int quad   = lane >> 4;
  const int m      = lane & 15;
  const int tokblk = blockIdx.x * TPB;

  if (tid < 64) cnt[tid] = 0;

  // MFMA A-operand gather: lane holds A[row=m][k=quad*8+j]; two 16-token m-tiles.
  const float* apb = x + (size_t)(tokblk + mhalf * 32 + m) * DDIM + khalf * 512 + quad * 8;
  const short8* wsrc = (const short8*)wfrag;

  // a1b1 chain isolated in ahi; all cross terms in alo (verified numerics).
  f32x4 ahi[2][5], alo[2][5];
  #pragma unroll
  for (int mt = 0; mt < 2; ++mt)
    #pragma unroll
    for (int nt = 0; nt < 5; ++nt) { ahi[mt][nt] = 0.f; alo[mt][nt] = 0.f; }

  // depth-2 A ring: cur = A(ks), nx1 = A(ks+1), nx2 = A(ks+2)
  float4 cur[4], nx1[4], nx2[4];
  #pragma unroll
  for (int mt = 0; mt < 2; ++mt) {
    const float* p = apb + (size_t)(mt * 16) * DDIM;
    cur[mt * 2]     = *(const float4*)(p);
    cur[mt * 2 + 1] = *(const float4*)(p + 4);
    nx1[mt * 2]     = *(const float4*)(p + 32);
    nx1[mt * 2 + 1] = *(const float4*)(p + 36);
  }

  // Prologue: stage ks=0 B into buf0. chunk c = wv + 4*j; c<15 -> khalf0
  // frag c, c>=15 -> khalf1 frag c-15. Each chunk = one contiguous 1 KB frag.
  {
    short8 breg[8];
    #pragma unroll
    for (int j = 0; j < 8; ++j) {
      const int c = wv + 4 * j;
      if (c < 30) {
        const int ksg = (c < 15) ? 0 : 16;
        const int fr  = (c < 15) ? c : c - 15;
        breg[j] = wsrc[((size_t)ksg * 15 + fr) * 64 + lane];
      }
    }
    #pragma unroll
    for (int j = 0; j < 8; ++j) {
      const int c = wv + 4 * j;
      if (c < 30) bstage[c * 64 + lane] = breg[j];
    }
  }
  barrier_nodrain();

  for (int ks = 0; ks < 16; ++ks) {
    const int pb = ks & 1;
    // ---- VMEM issue, top of step: breg (ks+1) FIRST (stays oldest so the
    // ds_write's auto-wait is a counted vmcnt leaving A flying), then A (ks+2).
    short8 breg[8];
    if (ks < 15) {
      #pragma unroll
      for (int j = 0; j < 8; ++j) {
        const int c = wv + 4 * j;
        if (c < 30) {
          const int ksg = (c < 15) ? (ks + 1) : (16 + ks + 1);
          const int fr  = (c < 15) ? c : c - 15;
          breg[j] = wsrc[((size_t)ksg * 15 + fr) * 64 + lane];
        }
      }
    }
    if (ks < 14) {
      #pragma unroll
      for (int mt = 0; mt < 2; ++mt) {
        const float* p = apb + (size_t)(mt * 16) * DDIM + (ks + 2) * 32;
        nx2[mt * 2]     = *(const float4*)(p);
        nx2[mt * 2 + 1] = *(const float4*)(p + 4);
      }
    }
    // ---- split3 for both m-tiles (consumes cur, loaded 2 steps ago) ----
    short8 fa[2][3];
    #pragma unroll
    for (int mt = 0; mt < 2; ++mt) {
      float av[8] = {cur[mt*2].x, cur[mt*2].y, cur[mt*2].z, cur[mt*2].w,
                     cur[mt*2+1].x, cur[mt*2+1].y, cur[mt*2+1].z, cur[mt*2+1].w};
      split3(av, fa[mt][0], fa[mt][1], fa[mt][2]);
    }
    // ---- nt loop, per-nt fb streaming from buf[pb] ----
    const short8* bbase = &bstage[(size_t)pb * 1920 + (size_t)khalf * 15 * 64 + lane];
    short8 fb0 = bbase[0], fb1 = bbase[64], fb2 = bbase[128];
    #pragma unroll
    for (int nt = 0; nt < 5; ++nt) {
      short8 n0, n1, n2;
      if (nt < 4) {
        n0 = bbase[(nt + 1) * 192];
        n1 = bbase[(nt + 1) * 192 + 64];
        n2 = bbase[(nt + 1) * 192 + 128];
      }
      // 8-pass split MFMA: a1b1 -> hi; cross terms -> lo (a3b3 dropped).
      // Per-accumulator chain order preserved exactly (bit-exact).
      #pragma unroll
      for (int mt = 0; mt < 2; ++mt) {
        ahi[mt][nt] = __builtin_amdgcn_mfma_f32_16x16x32_bf16(fa[mt][0], fb0, ahi[mt][nt], 0, 0, 0);
        f32x4 c = alo[mt][nt];
        c = __builtin_amdgcn_mfma_f32_16x16x32_bf16(fa[mt][0], fb1, c, 0, 0, 0);
        c = __builtin_amdgcn_mfma_f32_16x16x32_bf16(fa[mt][1], fb0, c, 0, 0, 0);
        c = __builtin_amdgcn_mfma_f32_16x16x32_bf16(fa[mt][1], fb1, c, 0, 0, 0);
        c = __builtin_amdgcn_mfma_f32_16x16x32_bf16(fa[mt][0], fb2, c, 0, 0, 0);
        c = __builtin_amdgcn_mfma_f32_16x16x32_bf16(fa[mt][2], fb0, c, 0, 0, 0);
        c = __builtin_amdgcn_mfma_f32_16x16x32_bf16(fa[mt][1], fb2, c, 0, 0, 0);
        c = __builtin_amdgcn_mfma_f32_16x16x32_bf16(fa[mt][2], fb1, c, 0, 0, 0);
        alo[mt][nt] = c;
      }
      if (nt < 4) { fb0 = n0; fb1 = n1; fb2 = n2; }
    }
    // ---- publish next B to buf[pb^1]; one NO-DRAIN barrier per step ----
    if (ks < 15) {
      #pragma unroll
      for (int j = 0; j < 8; ++j) {
        const int c = wv + 4 * j;
        if (c < 30) bstage[(size_t)(pb ^ 1) * 1920 + c * 64 + lane] = breg[j];
      }
      barrier_nodrain();
      // rotate the A ring (register renames, no copies after regalloc)
      #pragma unroll
      for (int i = 0; i < 4; ++i) { cur[i] = nx1[i]; nx1[i] = nx2[i]; }
    }
  }

  // ---- K-half combine, verified order: el = S1; el += S0 ----
  // Union-safe: step 15 read only buf1 (bytes 30720+); el (22528 B) sits in
  // buf0, whose last readers retired at the end-of-ks=14 barrier.
  // C/D layout: col(n)=lane&15, row(m)=quad*4+reg
  if (khalf == 1) {
    #pragma unroll
    for (int mt = 0; mt < 2; ++mt)
      #pragma unroll
      for (int nt = 0; nt < 5; ++nt)
        #pragma unroll
        for (int r = 0; r < 4; ++r)
          el[(mhalf * 32 + mt * 16 + quad * 4 + r) * 88 + nt * 16 + m] = ahi[mt][nt][r] + alo[mt][nt][r];
  }
  __syncthreads();
  if (khalf == 0) {
    #pragma unroll
    for (int mt = 0; mt < 2; ++mt)
      #pragma unroll
      for (int nt = 0; nt < 5; ++nt)
        #pragma unroll
        for (int r = 0; r < 4; ++r) {
          const int idx = (mhalf * 32 + mt * 16 + quad * 4 + r) * 88 + nt * 16 + m;
          el[idx] += ahi[mt][nt][r] + alo[mt][nt][r];
        }
  }
  __syncthreads();

  // ---- epilogue: one token per thread (tid<64) ----
  if (tid < TPB) {
    const int t = tid;
    float* row = el + t * 88;
    const float g0 = row[64], g1 = row[65], g2 = row[66], g3 = row[67];
    int g = 0; float gb = g0;
    if (g1 > gb) { g = 1; gb = g1; }
    if (g2 > gb) { g = 2; gb = g2; }
    if (g3 > gb) { g = 3; gb = g3; }
    const int base = g << 4;
    float l[16];
    #pragma unroll
    for (int e = 0; e < 16; ++e) l[e] = row[base + e];
    int i1 = 0; float v1 = l[0];
    #pragma unroll
    for (int e = 1; e < 16; ++e) if (l[e] > v1) { i1 = e; v1 = l[e]; }
    int i2 = -1; float v2 = 0.f;
    #pragma unroll
    for (int e = 0; e < 16; ++e) {
      if (e == i1) continue;
      if (i2 < 0 || l[e] > v2) { i2 = e; v2 = l[e]; }
    }
    float pr[16]; float s = 0.f;
    #pragma unroll
    for (int e = 0; e < 16; ++e) { pr[e] = expf(l[e] - v1); s += pr[e]; }
    const float inv = 1.f / s;
    #pragma unroll
    for (int c = 0; c < 64; ++c) row[c] = 0.f;
    #pragma unroll
    for (int e = 0; e < 16; ++e) row[base + e] = pr[e] * inv;
    const size_t T = (size_t)tokblk + t;
    out[2*T]     = (float)(base + i1);
    out[2*T + 1] = (float)(base + i2);
    const float e2 = expf(v2 - v1);
    const float si = 1.f / (1.f + e2);
    out[OFF_SCORES + 2*T]     = si;
    out[OFF_SCORES + 2*T + 1] = e2 * si;
    atomicAdd(&cnt[base + i1], 1);
    atomicAdd(&cnt[base + i2], 1);
  }
  __syncthreads();

  // coalesced probs_full write (256 threads, 16 iters)
  for (int i = tid; i < TPB * 64; i += 256) {
    const int t = i >> 6, c = i & 63;
    out[OFF_PROBS + (((size_t)(tokblk + t)) << 6) + c] = el[t * 88 + c];
  }
  // block-partial importance & counts -> slot-spread global atomics
  // (512 blocks / 16 slots = 32-way contention, verified scheme)
  if (tid < 64) {
    const int e = tid;
    float s = 0.f;
    #pragma unroll 4
    for (int t = 0; t < TPB; ++t) s += el[t * 88 + e];
    const int slot = (blockIdx.x & (NSLOT - 1)) * 128;
    atomicAdd(&ws[slot + e], s);
    atomicAdd(&ws[slot + 64 + e], (float)cnt[e]);
  }

  // ---- fused finalize: last block reduces the slots (saves a dispatch) ----
  __syncthreads();   // drain this block's ws atomics (vmcnt(0) at barrier)
  if (tid == 0) {
    __threadfence();
    unsigned prev = __hip_atomic_fetch_add((unsigned*)(ws + 2048), 1u,
                                           __ATOMIC_ACQ_REL, __HIP_MEMORY_SCOPE_AGENT);
    cnt[64] = (prev == (unsigned)(NBLOCKS - 1)) ? 1 : 0;
  }
  __syncthreads();
  if (cnt[64] && tid < 64) {
    const int e = tid;
    float imp = 0.f, cf = 0.f;
    #pragma unroll
    for (int s = 0; s < NSLOT; ++s) {   // identical order to the old finalize
      imp += __hip_atomic_load(&ws[s * 128 + e],      __ATOMIC_RELAXED, __HIP_MEMORY_SCOPE_AGENT);
      cf  += __hip_atomic_load(&ws[s * 128 + 64 + e], __ATOMIC_RELAXED, __HIP_MEMORY_SCOPE_AGENT);
    }
    out[OFF_IMP  + e] = imp * (1.0f / 32768.0f);
    out[OFF_LOAD + e] = cf  * (1.0f / 65536.0f);   // counts sum == B*S*K
  }
}

extern "C" void kernel_launch(void* const* d_in, const int* in_sizes, int n_in,
                              void* d_out, int out_size, void* d_ws, size_t ws_size,
                              hipStream_t stream) {
  (void)in_sizes; (void)n_in; (void)out_size; (void)ws_size;
  const float* x  = (const float*)d_in[0];   // [8,4096,1024]
  const float* Wg = (const float*)d_in[1];   // [4,1024]
  const float* We = (const float*)d_in[2];   // [64,1024]
  float* out = (float*)d_out;
  float* ws  = (float*)d_ws;                 // NSLOT x 128 floats + ticket at [2048]
  hipLaunchKernelGGL(prep_kernel, dim3(160), dim3(64), 0, stream, Wg, We, ws);
  hipLaunchKernelGGL(router_kernel, dim3(NBLOCKS), dim3(256), 0, stream, x, out, ws);
}

// Round 9
// 207.138 us; speedup vs baseline: 1.1050x; 1.0991x over previous
//
#include <hip/hip_runtime.h>
#include <math.h>

// Problem constants (B=8,S=4096,D=1024,E=64,G=4,K=2, temperature=1)
#define TOKENS   32768
#define DDIM     1024
#define TPB      64                   // tokens per block
#define NBLOCKS  (TOKENS / TPB)       // 512 blocks x 256 threads (4 waves: khalf x mhalf)

// Output layout (flat float32, tuple concat: idx, scores, probs, importance, load)
#define OFF_SCORES 65536
#define OFF_PROBS  131072
#define OFF_IMP    2228224
#define OFF_LOAD   2228288

#define NSLOT 16              // atomic spreading for importance/load partials

typedef __attribute__((ext_vector_type(8))) short  short8;  // 8 bf16 = 4 VGPR (MFMA A/B frag)
typedef __attribute__((ext_vector_type(4))) float  f32x4;   // MFMA C/D frag
typedef __attribute__((ext_vector_type(4))) int    intx4;

// Pre-split W fragments: [ks(32)][nt(5)][lvl(3)][lane(64)] x 16B. 480 KB, L2-resident.
// Rows 0..63 = experts, 64..67 = groups, 68..79 = zero pad.
__device__ __attribute__((aligned(16))) short wfrag[32 * 5 * 3 * 64 * 8];

// bf16 round-to-nearest-even of x, returned as the fp32 bit pattern.
__device__ inline unsigned rne_hi(float x) {
  unsigned u = __float_as_uint(x);
  unsigned r = u + 0x7fffu + ((u >> 16) & 1u);
  return r & 0xffff0000u;
}

// Split x (fp32) into 3 RNE-bf16 terms: x = a1 + a2 + a3 + O(2^-27 |x|).
__device__ inline void split3(const float* xv, short8& f1, short8& f2, short8& f3) {
  int o1[4], o2[4], o3[4];
  #pragma unroll
  for (int p = 0; p < 4; ++p) {
    float x0 = xv[2*p], x1 = xv[2*p+1];
    unsigned h0 = rne_hi(x0), h1 = rne_hi(x1);
    o1[p] = (int)((h0 >> 16) | (h1 & 0xffff0000u));
    float r0 = x0 - __uint_as_float(h0);
    float r1 = x1 - __uint_as_float(h1);
    unsigned g0 = rne_hi(r0), g1 = rne_hi(r1);
    o2[p] = (int)((g0 >> 16) | (g1 & 0xffff0000u));
    float s0 = r0 - __uint_as_float(g0);
    float s1 = r1 - __uint_as_float(g1);
    unsigned w0 = rne_hi(s0), w1 = rne_hi(s1);
    o3[p] = (int)((w0 >> 16) | (w1 & 0xffff0000u));
  }
  intx4 t1 = {o1[0], o1[1], o1[2], o1[3]};
  intx4 t2 = {o2[0], o2[1], o2[2], o2[3]};
  intx4 t3 = {o3[0], o3[1], o3[2], o3[3]};
  f1 = __builtin_bit_cast(short8, t1);
  f2 = __builtin_bit_cast(short8, t2);
  f3 = __builtin_bit_cast(short8, t3);
}

// Build W fragment splits. 160 blocks (nt*32+ks) x 64 threads.
// Blocks 0..31 also zero the ws accumulators (replaces the hipMemsetAsync).
__global__ void prep_kernel(const float* __restrict__ Wg, const float* __restrict__ We,
                            float* __restrict__ ws) {
  const int nt   = blockIdx.x >> 5;   // 0..4
  const int ks   = blockIdx.x & 31;   // 0..31
  const int lane = threadIdx.x & 63;
  if (blockIdx.x < 32) ws[blockIdx.x * 64 + lane] = 0.f;   // NSLOT*128 = 2048 floats
  const int row  = nt * 16 + (lane & 15);
  const int k0   = ks * 32 + (lane >> 4) * 8;
  float xv[8];
  #pragma unroll
  for (int j = 0; j < 8; ++j) {
    float v = 0.f;
    if (row < 64)      v = We[(size_t)row * DDIM + k0 + j];
    else if (row < 68) v = Wg[(size_t)(row - 64) * DDIM + k0 + j];
    xv[j] = v;
  }
  short8 f1, f2, f3;
  split3(xv, f1, f2, f3);
  short8* dst = (short8*)wfrag + (((size_t)ks * 5 + nt) * 3) * 64 + lane;
  dst[0]   = f1;
  dst[64]  = f2;
  dst[128] = f3;
}

// R9 = exact restoration of the session-best R4 configuration (205.8 us).
// Bit-exact per-token arithmetic vs the verified kernel: identical per-
// accumulator MFMA chain order, sequential ks per khalf, el=S1; el+=S0
// combine, identical epilogue, slot-spread ws atomics + separate finalize.
// Session attribution (kept OUT of this kernel, each measured harmful/null):
//  - ticket-fused finalize: ~+20 us (per-block device-scope fence+ACQ_REL
//    atomic = cross-XCD L2 writeback per block; R6/R8 both ~228),
//  - global_load_lds B-staging: +10 us (DMA completion serialized on the
//    per-step barrier drain; R6),
//  - no-drain barrier / depth-2 A-ring: null alone and null combined
//    (R5 208.9, R8 router 83 vs R4 <77),
//  - ksplit=4 (2 waves/SIMD + full B-amortization): FORBIDDEN — fp32
//    reassociation flips top-k ties (R7 fail). The summation association
//    is untouchable.
__global__ __launch_bounds__(256)
__attribute__((amdgpu_waves_per_eu(2)))
void router_kernel(const float* __restrict__ x,
                   float* __restrict__ out,
                   float* __restrict__ ws) {
  // union: [0,61440) = bstage dbuf (2 x 30 chunks x 64 lanes x 16B);
  //        el (64*88*4 = 22528 B) overlays buf0, used only after the loop.
  __shared__ __attribute__((aligned(16))) char smem[61440 + 256];
  float*  el     = (float*)smem;
  short8* bstage = (short8*)smem;
  int*    cnt    = (int*)(smem + 61440);
  const int tid    = threadIdx.x;
  const int lane   = tid & 63;
  const int wv     = tid >> 6;      // 0..3
  const int khalf  = wv >> 1;       // K-half (512-wide, sequential 16 k-steps)
  const int mhalf  = wv & 1;        // which pair of 16-token m-tiles
  const int quad   = lane >> 4;
  const int m      = lane & 15;
  const int tokblk = blockIdx.x * TPB;

  if (tid < 64) cnt[tid] = 0;

  // MFMA A-operand gather: lane holds A[row=m][k=quad*8+j]; two 16-token m-tiles.
  const float* apb = x + (size_t)(tokblk + mhalf * 32 + m) * DDIM + khalf * 512 + quad * 8;
  const short8* wsrc = (const short8*)wfrag;

  // a1b1 chain isolated in ahi; all cross terms in alo (verified numerics).
  f32x4 ahi[2][5], alo[2][5];
  #pragma unroll
  for (int mt = 0; mt < 2; ++mt)
    #pragma unroll
    for (int nt = 0; nt < 5; ++nt) { ahi[mt][nt] = 0.f; alo[mt][nt] = 0.f; }

  // A for ks=0
  float4 cur[4], nxt[4];
  #pragma unroll
  for (int mt = 0; mt < 2; ++mt) {
    const float* p = apb + (size_t)(mt * 16) * DDIM;
    cur[mt * 2]     = *(const float4*)(p);
    cur[mt * 2 + 1] = *(const float4*)(p + 4);
  }

  // Prologue: stage ks=0 B into buf0. chunk c = wv + 4*j; c<15 -> khalf0
  // frag c, c>=15 -> khalf1 frag c-15. Each chunk = one contiguous 1 KB frag.
  {
    short8 breg[8];
    #pragma unroll
    for (int j = 0; j < 8; ++j) {
      const int c = wv + 4 * j;
      if (c < 30) {
        const int ksg = (c < 15) ? 0 : 16;
        const int fr  = (c < 15) ? c : c - 15;
        breg[j] = wsrc[((size_t)ksg * 15 + fr) * 64 + lane];
      }
    }
    #pragma unroll
    for (int j = 0; j < 8; ++j) {
      const int c = wv + 4 * j;
      if (c < 30) bstage[c * 64 + lane] = breg[j];
    }
  }
  __syncthreads();

  for (int ks = 0; ks < 16; ++ks) {
    const int pb = ks & 1;
    // ---- VMEM issue, top of step: breg (ks+1) first, then A (ks+1) ----
    short8 breg[8];
    if (ks < 15) {
      #pragma unroll
      for (int j = 0; j < 8; ++j) {
        const int c = wv + 4 * j;
        if (c < 30) {
          const int ksg = (c < 15) ? (ks + 1) : (16 + ks + 1);
          const int fr  = (c < 15) ? c : c - 15;
          breg[j] = wsrc[((size_t)ksg * 15 + fr) * 64 + lane];
        }
      }
    }
    const int kpf = (ks + 1 < 16) ? (ks + 1) : 15;
    #pragma unroll
    for (int mt = 0; mt < 2; ++mt) {
      const float* p = apb + (size_t)(mt * 16) * DDIM + kpf * 32;
      nxt[mt * 2]     = *(const float4*)(p);
      nxt[mt * 2 + 1] = *(const float4*)(p + 4);
    }
    // ---- split3 for both m-tiles ----
    short8 fa[2][3];
    #pragma unroll
    for (int mt = 0; mt < 2; ++mt) {
      float av[8] = {cur[mt*2].x, cur[mt*2].y, cur[mt*2].z, cur[mt*2].w,
                     cur[mt*2+1].x, cur[mt*2+1].y, cur[mt*2+1].z, cur[mt*2+1].w};
      split3(av, fa[mt][0], fa[mt][1], fa[mt][2]);
    }
    // ---- nt loop, per-nt fb streaming from buf[pb] ----
    const short8* bbase = &bstage[(size_t)pb * 1920 + (size_t)khalf * 15 * 64 + lane];
    short8 fb0 = bbase[0], fb1 = bbase[64], fb2 = bbase[128];
    #pragma unroll
    for (int nt = 0; nt < 5; ++nt) {
      short8 n0, n1, n2;
      if (nt < 4) {
        n0 = bbase[(nt + 1) * 192];
        n1 = bbase[(nt + 1) * 192 + 64];
        n2 = bbase[(nt + 1) * 192 + 128];
      }
      // 8-pass split MFMA: a1b1 -> hi; cross terms -> lo (a3b3 dropped).
      // Per-accumulator chain order preserved exactly (bit-exact).
      #pragma unroll
      for (int mt = 0; mt < 2; ++mt) {
        ahi[mt][nt] = __builtin_amdgcn_mfma_f32_16x16x32_bf16(fa[mt][0], fb0, ahi[mt][nt], 0, 0, 0);
        f32x4 c = alo[mt][nt];
        c = __builtin_amdgcn_mfma_f32_16x16x32_bf16(fa[mt][0], fb1, c, 0, 0, 0);
        c = __builtin_amdgcn_mfma_f32_16x16x32_bf16(fa[mt][1], fb0, c, 0, 0, 0);
        c = __builtin_amdgcn_mfma_f32_16x16x32_bf16(fa[mt][1], fb1, c, 0, 0, 0);
        c = __builtin_amdgcn_mfma_f32_16x16x32_bf16(fa[mt][0], fb2, c, 0, 0, 0);
        c = __builtin_amdgcn_mfma_f32_16x16x32_bf16(fa[mt][2], fb0, c, 0, 0, 0);
        c = __builtin_amdgcn_mfma_f32_16x16x32_bf16(fa[mt][1], fb2, c, 0, 0, 0);
        c = __builtin_amdgcn_mfma_f32_16x16x32_bf16(fa[mt][2], fb1, c, 0, 0, 0);
        alo[mt][nt] = c;
      }
      if (nt < 4) { fb0 = n0; fb1 = n1; fb2 = n2; }
    }
    // ---- publish next B to buf[pb^1]; single barrier per step ----
    if (ks < 15) {
      #pragma unroll
      for (int j = 0; j < 8; ++j) {
        const int c = wv + 4 * j;
        if (c < 30) bstage[(size_t)(pb ^ 1) * 1920 + c * 64 + lane] = breg[j];
      }
      __syncthreads();
    }
    #pragma unroll
    for (int i = 0; i < 4; ++i) cur[i] = nxt[i];
  }

  // ---- K-half combine, verified order: el = S1; el += S0 ----
  // Safe vs the union: step 15 read only buf1 (bytes 30720+); el is 22528 B
  // inside buf0, whose last readers retired at the end-of-ks=14 barrier.
  // C/D layout: col(n)=lane&15, row(m)=quad*4+reg
  if (khalf == 1) {
    #pragma unroll
    for (int mt = 0; mt < 2; ++mt)
      #pragma unroll
      for (int nt = 0; nt < 5; ++nt)
        #pragma unroll
        for (int r = 0; r < 4; ++r)
          el[(mhalf * 32 + mt * 16 + quad * 4 + r) * 88 + nt * 16 + m] = ahi[mt][nt][r] + alo[mt][nt][r];
  }
  __syncthreads();
  if (khalf == 0) {
    #pragma unroll
    for (int mt = 0; mt < 2; ++mt)
      #pragma unroll
      for (int nt = 0; nt < 5; ++nt)
        #pragma unroll
        for (int r = 0; r < 4; ++r) {
          const int idx = (mhalf * 32 + mt * 16 + quad * 4 + r) * 88 + nt * 16 + m;
          el[idx] += ahi[mt][nt][r] + alo[mt][nt][r];
        }
  }
  __syncthreads();

  // ---- epilogue: one token per thread (tid<64) ----
  if (tid < TPB) {
    const int t = tid;
    float* row = el + t * 88;
    const float g0 = row[64], g1 = row[65], g2 = row[66], g3 = row[67];
    int g = 0; float gb = g0;
    if (g1 > gb) { g = 1; gb = g1; }
    if (g2 > gb) { g = 2; gb = g2; }
    if (g3 > gb) { g = 3; gb = g3; }
    const int base = g << 4;
    float l[16];
    #pragma unroll
    for (int e = 0; e < 16; ++e) l[e] = row[base + e];
    int i1 = 0; float v1 = l[0];
    #pragma unroll
    for (int e = 1; e < 16; ++e) if (l[e] > v1) { i1 = e; v1 = l[e]; }
    int i2 = -1; float v2 = 0.f;
    #pragma unroll
    for (int e = 0; e < 16; ++e) {
      if (e == i1) continue;
      if (i2 < 0 || l[e] > v2) { i2 = e; v2 = l[e]; }
    }
    float pr[16]; float s = 0.f;
    #pragma unroll
    for (int e = 0; e < 16; ++e) { pr[e] = expf(l[e] - v1); s += pr[e]; }
    const float inv = 1.f / s;
    #pragma unroll
    for (int c = 0; c < 64; ++c) row[c] = 0.f;
    #pragma unroll
    for (int e = 0; e < 16; ++e) row[base + e] = pr[e] * inv;
    const size_t T = (size_t)tokblk + t;
    out[2*T]     = (float)(base + i1);
    out[2*T + 1] = (float)(base + i2);
    const float e2 = expf(v2 - v1);
    const float si = 1.f / (1.f + e2);
    out[OFF_SCORES + 2*T]     = si;
    out[OFF_SCORES + 2*T + 1] = e2 * si;
    atomicAdd(&cnt[base + i1], 1);
    atomicAdd(&cnt[base + i2], 1);
  }
  __syncthreads();

  // coalesced probs_full write (256 threads, 16 iters)
  for (int i = tid; i < TPB * 64; i += 256) {
    const int t = i >> 6, c = i & 63;
    out[OFF_PROBS + (((size_t)(tokblk + t)) << 6) + c] = el[t * 88 + c];
  }
  // block-partial importance & counts -> slot-spread global atomics
  // (512 blocks / 16 slots = 32-way contention, verified scheme)
  if (tid < 64) {
    const int e = tid;
    float s = 0.f;
    #pragma unroll 4
    for (int t = 0; t < TPB; ++t) s += el[t * 88 + e];
    const int slot = (blockIdx.x & (NSLOT - 1)) * 128;
    atomicAdd(&ws[slot + e], s);
    atomicAdd(&ws[slot + 64 + e], (float)cnt[e]);
  }
}

__global__ void finalize_kernel(const float* __restrict__ ws, float* __restrict__ out) {
  const int e = threadIdx.x;
  if (e < 64) {
    float imp = 0.f, cf = 0.f;
    #pragma unroll
    for (int s = 0; s < NSLOT; ++s) {
      imp += ws[s * 128 + e];
      cf  += ws[s * 128 + 64 + e];
    }
    out[OFF_IMP  + e] = imp * (1.0f / 32768.0f);
    out[OFF_LOAD + e] = cf  * (1.0f / 65536.0f);   // counts sum == B*S*K
  }
}

extern "C" void kernel_launch(void* const* d_in, const int* in_sizes, int n_in,
                              void* d_out, int out_size, void* d_ws, size_t ws_size,
                              hipStream_t stream) {
  (void)in_sizes; (void)n_in; (void)out_size; (void)ws_size;
  const float* x  = (const float*)d_in[0];   // [8,4096,1024]
  const float* Wg = (const float*)d_in[1];   // [4,1024]
  const float* We = (const float*)d_in[2];   // [64,1024]
  float* out = (float*)d_out;
  float* ws  = (float*)d_ws;                 // NSLOT x (64 importance + 64 counts)
  hipLaunchKernelGGL(prep_kernel, dim3(160), dim3(64), 0, stream, Wg, We, ws);
  hipLaunchKernelGGL(router_kernel, dim3(NBLOCKS), dim3(256), 0, stream, x, out, ws);
  hipLaunchKernelGGL(finalize_kernel, dim3(1), dim3(64), 0, stream, ws, out);
}